// Round 1
// baseline (1540.002 us; speedup 1.0000x reference)
//
#include <hip/hip_runtime.h>

// VanillaLSTM fused: T=64 steps, one kernel, 2 sequences per thread packed as
// <2 x float> so the fp32 math maps to v_pk_fma_f32 (2x fp32 rate on CDNA4).
// Weights are wave-uniform -> compiler scalarizes to s_load (K$-resident,
// 10.5 KB total), leaving VALU slots for the FMAs.

typedef float v2f __attribute__((ext_vector_type(2)));

#define TSTEPS 64
#define H 20
#define M 10

__device__ __forceinline__ v2f sp(float s){ v2f r; r.x = s; r.y = s; return r; }
__device__ __forceinline__ v2f mk(float a, float b){ v2f r; r.x = a; r.y = b; return r; }

__device__ __forceinline__ float sigm1(float x){
    // 1 / (1 + exp(-x)) : v_exp_f32 + v_rcp_f32, ~1ulp each
    return __builtin_amdgcn_rcpf(1.0f + __expf(-x));
}
__device__ __forceinline__ v2f sigm(v2f x){ return mk(sigm1(x.x), sigm1(x.y)); }

__device__ __forceinline__ float tanh1(float x){
    // tanh(x) = 1 - 2/(exp(2x)+1); saturates correctly at +-inf
    return 1.0f - 2.0f * __builtin_amdgcn_rcpf(__expf(2.0f * x) + 1.0f);
}
__device__ __forceinline__ v2f tanhv(v2f x){ return mk(tanh1(x.x), tanh1(x.y)); }

__global__ __launch_bounds__(256)
void lstm_fused(const float* __restrict__ X,
                const int*   __restrict__ pm,
                const float* __restrict__ h0,
                const float* __restrict__ c0,
                const float* __restrict__ Yv,
                const int*   __restrict__ tobs_p,
                const int*   __restrict__ tpred_p,
                const float* __restrict__ W_in,  const float* __restrict__ b_in,
                const float* __restrict__ W_ih,  const float* __restrict__ W_hh,
                const float* __restrict__ b_ih,  const float* __restrict__ b_hh,
                const float* __restrict__ W_out, const float* __restrict__ b_out,
                float* __restrict__ outp, int N)
{
    const int tid  = blockIdx.x * blockDim.x + threadIdx.x;
    const int half = N >> 1;
    if (tid >= half) return;
    const int n0 = tid;            // lane's sequence A
    const int n1 = tid + half;     // lane's sequence B (split-half keeps both streams coalesced)
    const int T_obs  = *tobs_p;
    const int T_pred = *tpred_p;

    // --- recurrent state in registers (packed: .x = seq A, .y = seq B) ---
    v2f h[H], c[H];
#pragma unroll
    for (int j = 0; j < H; ++j){
        h[j] = mk(h0[(size_t)n0*H + j], h0[(size_t)n1*H + j]);
        c[j] = mk(c0[(size_t)n0*H + j], c0[(size_t)n1*H + j]);
    }

    // m_prev3 rolling queue (rows 0..2 are ones)
    v2f q0 = sp(1.f), q1 = sp(1.f), q2 = sp(1.f);
    // prev output (D_OUT=2 components, each packed over 2 seqs)
    v2f po0 = sp(0.f), po1 = sp(0.f);

    // software-pipelined loads for step t
    int pm0 = pm[n0];
    int pm1 = pm[n1];
    v2f x0, x1;
    {
        v2f xa = *(const v2f*)(X + ((size_t)0*N + n0)*4 + 2);
        v2f xb = *(const v2f*)(X + ((size_t)0*N + n1)*4 + 2);
        x0 = mk(xa.x, xb.x);   // feature 0 for (A,B)
        x1 = mk(xa.y, xb.y);   // feature 1 for (A,B)
    }

#pragma unroll 1
    for (int t = 0; t < TSTEPS; ++t){
        const v2f mt  = mk((float)pm0, (float)pm1);
        const v2f mp3 = q0; q0 = q1; q1 = q2; q2 = mt;

        v2f in0, in1;
        if (t <= T_obs){ in0 = x0; in1 = x1; }       // uniform branch
        else           { in0 = po0; in1 = po1; }

        // ---- prefetch next step's mask / X (hides HBM latency under compute) ----
        if (t + 1 < TSTEPS){
            pm0 = pm[(size_t)(t+1)*N + n0];
            pm1 = pm[(size_t)(t+1)*N + n1];
            if (t + 1 <= T_obs){
                v2f xa = *(const v2f*)(X + ((size_t)(t+1)*N + n0)*4 + 2);
                v2f xb = *(const v2f*)(X + ((size_t)(t+1)*N + n1)*4 + 2);
                x0 = mk(xa.x, xb.x);
                x1 = mk(xa.y, xb.y);
            }
        }

        // ---- early Y fetch for overwrite lanes (condition known from masks) ----
        const bool ow_u = (t > 3) && (t > T_obs);    // uniform part
        bool ow_a = false, ow_b = false;
        v2f y0 = sp(0.f), y1 = sp(0.f);
        if (ow_u){
            ow_a = (mt.x != 0.f) && (mp3.x == 0.f);
            ow_b = (mt.y != 0.f) && (mp3.y == 0.f);
            if (ow_a){ v2f ya = *(const v2f*)(Yv + ((size_t)t*N + n0)*2); y0.x = ya.x; y1.x = ya.y; }
            if (ow_b){ v2f yb = *(const v2f*)(Yv + ((size_t)t*N + n1)*2); y0.y = yb.x; y1.y = yb.y; }
        }

        // ---- r = relu(inp @ W_in.T + b_in) : (2 seqs) x M ----
        v2f r[M];
#pragma unroll
        for (int mm = 0; mm < M; ++mm){
            v2f a = sp(b_in[mm]);
            a += sp(W_in[mm*2 + 0]) * in0;
            a += sp(W_in[mm*2 + 1]) * in1;
            r[mm] = mk(fmaxf(a.x, 0.f), fmaxf(a.y, 0.f));
        }

        const bool active = (t <= T_pred);           // uniform

        // ---- gates + cell update, one hidden unit at a time (fully unrolled:
        //      all h/c/hn indices compile-time -> stays in VGPRs) ----
        v2f hn[H];
#pragma unroll
        for (int jj = 0; jj < H; ++jj){
            v2f ai = sp(b_ih[jj]        + b_hh[jj]);
            v2f af = sp(b_ih[H + jj]    + b_hh[H + jj]);
            v2f ag = sp(b_ih[2*H + jj]  + b_hh[2*H + jj]);
            v2f ao = sp(b_ih[3*H + jj]  + b_hh[3*H + jj]);
#pragma unroll
            for (int k = 0; k < M; ++k){
                const v2f rk = r[k];
                ai += sp(W_ih[(jj      )*M + k]) * rk;
                af += sp(W_ih[(H   + jj)*M + k]) * rk;
                ag += sp(W_ih[(2*H + jj)*M + k]) * rk;
                ao += sp(W_ih[(3*H + jj)*M + k]) * rk;
            }
#pragma unroll
            for (int k = 0; k < H; ++k){
                const v2f hk = h[k];
                ai += sp(W_hh[(jj      )*H + k]) * hk;
                af += sp(W_hh[(H   + jj)*H + k]) * hk;
                ag += sp(W_hh[(2*H + jj)*H + k]) * hk;
                ao += sp(W_hh[(3*H + jj)*H + k]) * hk;
            }
            const v2f cn = sigm(af) * c[jj] + sigm(ai) * tanhv(ag);
            const v2f hv = sigm(ao) * tanhv(cn);
            if (active) c[jj] = cn;                  // uniform predicate
            hn[jj] = hv;
        }

        // ---- out = (h_new @ W_out.T + b_out) * m ----
        v2f o0 = sp(b_out[0]), o1 = sp(b_out[1]);
#pragma unroll
        for (int k = 0; k < H; ++k){
            o0 += sp(W_out[k    ]) * hn[k];
            o1 += sp(W_out[H + k]) * hn[k];
        }
        o0 *= mt; o1 *= mt;

        if (ow_a){ o0.x = y0.x; o1.x = y1.x; }
        if (ow_b){ o0.y = y0.y; o1.y = y1.y; }

        if (active){
#pragma unroll
            for (int j = 0; j < H; ++j) h[j] = hn[j];
        } else {
            o0 = sp(0.f); o1 = sp(0.f);              // out zeroed, h/c frozen
        }

        *(v2f*)(outp + ((size_t)t*N + n0)*2) = mk(o0.x, o1.x);
        *(v2f*)(outp + ((size_t)t*N + n1)*2) = mk(o0.y, o1.y);
        po0 = o0; po1 = o1;
    }
}

extern "C" void kernel_launch(void* const* d_in, const int* in_sizes, int n_in,
                              void* d_out, int out_size, void* d_ws, size_t ws_size,
                              hipStream_t stream)
{
    const float* X     = (const float*)d_in[0];
    const int*   pmk   = (const int*)  d_in[1];
    const float* h0    = (const float*)d_in[2];
    const float* c0    = (const float*)d_in[3];
    const float* Yv    = (const float*)d_in[4];
    const int*   tobs  = (const int*)  d_in[5];
    const int*   tpred = (const int*)  d_in[6];
    const float* W_in  = (const float*)d_in[7];
    const float* b_in  = (const float*)d_in[8];
    const float* W_ih  = (const float*)d_in[9];
    const float* W_hh  = (const float*)d_in[10];
    const float* b_ih  = (const float*)d_in[11];
    const float* b_hh  = (const float*)d_in[12];
    const float* W_out = (const float*)d_in[13];
    const float* b_out = (const float*)d_in[14];
    float* outp = (float*)d_out;

    const int N = in_sizes[1] / TSTEPS;   // part_masks is (T,1,N)
    const int threads = N / 2;            // 2 sequences per thread (packed fp32)
    const int block = 256;
    const int grid = (threads + block - 1) / block;

    hipLaunchKernelGGL(lstm_fused, dim3(grid), dim3(block), 0, stream,
                       X, pmk, h0, c0, Yv, tobs, tpred,
                       W_in, b_in, W_ih, W_hh, b_ih, b_hh, W_out, b_out,
                       outp, N);
}